// Round 3
// baseline (671.152 us; speedup 1.0000x reference)
//
#include <hip/hip_runtime.h>

typedef __attribute__((ext_vector_type(8))) short short8;
typedef __attribute__((ext_vector_type(4))) float floatx4;

// ---------- bf16 helpers ----------
__device__ __forceinline__ float bf2f(unsigned short u) {
  union { unsigned int i; float f; } v; v.i = ((unsigned int)u) << 16; return v.f;
}
__device__ __forceinline__ unsigned short f2bf(float f) {
  union { float f; unsigned int i; } v; v.f = f;
  unsigned int x = v.i + 0x7fffu + ((v.i >> 16) & 1u);
  return (unsigned short)(x >> 16);
}
__device__ __forceinline__ float loadE(const void* p, size_t i, int f) {
  return f ? ((const float*)p)[i] : bf2f(((const unsigned short*)p)[i]);
}
__device__ __forceinline__ uint4 packbf(float4 a, float4 b) {
  union { unsigned short u[8]; uint4 v; } p;
  p.u[0] = f2bf(a.x); p.u[1] = f2bf(a.y); p.u[2] = f2bf(a.z); p.u[3] = f2bf(a.w);
  p.u[4] = f2bf(b.x); p.u[5] = f2bf(b.y); p.u[6] = f2bf(b.z); p.u[7] = f2bf(b.w);
  return p.v;
}

// ---------- dtype detect ----------
__global__ void detect_kernel(const unsigned int* __restrict__ probe, int* __restrict__ flag) {
  if (threadIdx.x == 0 && blockIdx.x == 0) *flag = (probe[0] == 0x3F800000u) ? 1 : 0;
}

// ---------- zero d_out (dtype-aware) ----------
__global__ __launch_bounds__(256) void zero_kernel(void* __restrict__ out, int out_elems,
                                                   const int* __restrict__ flagp) {
  int limit = (*flagp) ? (out_elems >> 2) : (out_elems >> 3);  // uint4 chunks
  int i = blockIdx.x * 256 + threadIdx.x;
  if (i < limit) ((uint4*)out)[i] = make_uint4(0, 0, 0, 0);
}

// ---------- LayerNorm over both external inputs -> unified bf16 (c rows first) ----------
__global__ __launch_bounds__(256) void ln_ext_kernel(const void* __restrict__ cin,
                                                     const void* __restrict__ xin,
                                                     unsigned short* __restrict__ out,
                                                     const int* __restrict__ flagp) {
  const int D = 1024, S = 512;
  const int flag = *flagp;
  int row = blockIdx.x;
  const void* src = (row < S) ? cin : xin;
  size_t rb = (size_t)(row < S ? row : row - S) * D;
  int base = threadIdx.x * 4;
  float x0 = loadE(src, rb + base + 0, flag);
  float x1 = loadE(src, rb + base + 1, flag);
  float x2 = loadE(src, rb + base + 2, flag);
  float x3 = loadE(src, rb + base + 3, flag);
  float s1 = x0 + x1 + x2 + x3;
  float s2 = x0 * x0 + x1 * x1 + x2 * x2 + x3 * x3;
  for (int off = 32; off; off >>= 1) {
    s1 += __shfl_down(s1, off, 64);
    s2 += __shfl_down(s2, off, 64);
  }
  __shared__ float red[8];
  int wid = threadIdx.x >> 6;
  if ((threadIdx.x & 63) == 0) { red[wid] = s1; red[4 + wid] = s2; }
  __syncthreads();
  s1 = red[0] + red[1] + red[2] + red[3];
  s2 = red[4] + red[5] + red[6] + red[7];
  float mean = s1 * (1.0f / D);
  float var = s2 * (1.0f / D) - mean * mean;
  float inv = rsqrtf(var + 1e-6f);
  unsigned short* dst = out + (size_t)row * D + base;
  dst[0] = f2bf((x0 - mean) * inv);
  dst[1] = f2bf((x1 - mean) * inv);
  dst[2] = f2bf((x2 - mean) * inv);
  dst[3] = f2bf((x3 - mean) * inv);
}

// ---------- LayerNorm over internal bf16 mid; split outputs ----------
__global__ __launch_bounds__(256) void ln_mid_kernel(const unsigned short* __restrict__ in,
                                                     unsigned short* __restrict__ outc,
                                                     unsigned short* __restrict__ outx) {
  const int D = 1024, S = 512;
  int row = blockIdx.x;
  const unsigned short* src = in + (size_t)row * D;
  int base = threadIdx.x * 4;
  float x0 = bf2f(src[base + 0]);
  float x1 = bf2f(src[base + 1]);
  float x2 = bf2f(src[base + 2]);
  float x3 = bf2f(src[base + 3]);
  float s1 = x0 + x1 + x2 + x3;
  float s2 = x0 * x0 + x1 * x1 + x2 * x2 + x3 * x3;
  for (int off = 32; off; off >>= 1) {
    s1 += __shfl_down(s1, off, 64);
    s2 += __shfl_down(s2, off, 64);
  }
  __shared__ float red[8];
  int wid = threadIdx.x >> 6;
  if ((threadIdx.x & 63) == 0) { red[wid] = s1; red[4 + wid] = s2; }
  __syncthreads();
  s1 = red[0] + red[1] + red[2] + red[3];
  s2 = red[4] + red[5] + red[6] + red[7];
  float mean = s1 * (1.0f / D);
  float var = s2 * (1.0f / D) - mean * mean;
  float inv = rsqrtf(var + 1e-6f);
  unsigned short* dst = (row < S ? outc + (size_t)row * D : outx + (size_t)(row - S) * D) + base;
  dst[0] = f2bf((x0 - mean) * inv);
  dst[1] = f2bf((x1 - mean) * inv);
  dst[2] = f2bf((x2 - mean) * inv);
  dst[3] = f2bf((x3 - mean) * inv);
}

// ---------- multi-descriptor register-pipelined GEMM ----------
// C[M,N] = A[M,K](bf16 internal) @ B[N,K]^T(external dual dtype, converted in staging).
// 128x128 tile, BK=32, regs stage t+1, LDS double-buffer (pad 40 hw), 4 waves, 4x4 mfma.
// Round-2 fix: on the fp32-B path (the LIVE path), packbf() used to consume the loads
// at the ISSUE site inside load_tile -> compiler placed the vmcnt wait right after
// issue = full ~900cyc memory-latency stall every tile (why every dispatch sat at
// ~106us / MfmaUtil 6% regardless of FLOPs, and why barrier changes were neutral).
// Now load_tile only issues loads (raw float4 regs, live only on the f32 branch);
// the pack happens in store_tile one iteration later, so the wait is covered by
// BAR+compute+BAR. sched_barrier(0) after BAR#1 stops hipcc hoisting the register-
// only pack back into the compute phase (ERRATA rule #18 hoist hazard).
// Single prefetch set only -- round-0's 2-set version spilled (VGPR capped 64).
// Descriptors: up to 4 sub-GEMMs; blockIdx.y -> desc via cumulative m-tiles. Per-desc N.
// RES_MODE: 0 none, 1 += external dual res, 3 out=silu(bf16 res)*(acc+bias), 4 += bf16 res.
// OUT_MODE: 0 internal bf16, 2 external dual. SPLITK>1 (OUT 2 only): fp32 atomicAdd slices
// (bias/res added by slice 0); bf16-out fallback: slice 0 does full K, others exit.
struct GArgs {
  const unsigned short* A[4];
  const void* B[4];
  const void* bias[4];
  const void* res[4];
  void* C[4];
  unsigned long long oo[4];
  int mcum[4];  // cumulative m-tile counts
  int N[4];
  int K;
  int nd;
};

// LDS-only fence + barrier. Deliberately does NOT drain vmcnt: in-flight global
// prefetch survives the barrier (T3/T4 counted-wait principle).
#define BAR() asm volatile("s_waitcnt lgkmcnt(0)\n\ts_barrier" ::: "memory")

template <int RES_MODE, int OUT_MODE, int SPLITK>
__global__ __launch_bounds__(256) void gemm_kernel(GArgs g, const int* __restrict__ flagp) {
  const int flag = *flagp;
  // descriptor select
  int by = blockIdx.y;
  int d = 0;
  while (d < g.nd - 1 && by >= g.mcum[d]) ++d;
  int mbase = (d == 0) ? 0 : g.mcum[d - 1];
  const int m0 = (by - mbase) * 128;
  const int N = g.N[d];
  const int n0 = blockIdx.x * 128;
  if (n0 >= N) return;  // block-uniform
  const int K = g.K;
  // K slice
  int kbeg = 0, kend = K;
  if (SPLITK > 1) {
    if (!flag) {
      if (blockIdx.z != 0) return;
    } else {
      int kl = K / SPLITK;
      kbeg = blockIdx.z * kl;
      kend = kbeg + kl;
    }
  }
  const int nt = (kend - kbeg) >> 5;

  __shared__ __align__(16) unsigned short sA[2 * 5120];  // 128 rows x 40 hw, 2 buffers
  __shared__ __align__(16) unsigned short sB[2 * 5120];

  const int tid = threadIdx.x;
  const int lane = tid & 63;
  const int wave = tid >> 6;
  const int wm = (wave >> 1) * 64, wn = (wave & 1) * 64;
  // staging assignment: chunk c in {tid, tid+256}; row=c>>2 (0..127), colblk=c&3 (8 hw)
  const int srow = tid >> 2;
  const int scol = (tid & 3) * 8;
  const int wo0 = srow * 40 + scol;
  const int wo1 = wo0 + 64 * 40;
  const unsigned short* Ag0 = g.A[d] + (size_t)(m0 + srow) * K + kbeg + scol;
  const unsigned short* Ag1 = Ag0 + (size_t)64 * K;
  const unsigned short* Bh0 = (const unsigned short*)g.B[d] + (size_t)(n0 + srow) * K + kbeg + scol;
  const unsigned short* Bh1 = Bh0 + (size_t)64 * K;
  const float* Bf0 = (const float*)g.B[d] + (size_t)(n0 + srow) * K + kbeg + scol;
  const float* Bf1 = Bf0 + (size_t)64 * K;

  uint4 ra0, ra1;              // A prefetch (bf16, both paths)
  uint4 rb0, rb1;              // B prefetch, bf16 path only
  float4 fx0, fx1, fy0, fy1;   // B prefetch, f32 path only (pack deferred to store)
  auto load_tile = [&](int kk) {
    ra0 = *(const uint4*)(Ag0 + kk);
    ra1 = *(const uint4*)(Ag1 + kk);
    if (flag) {
      fx0 = *(const float4*)(Bf0 + kk);
      fx1 = *(const float4*)(Bf0 + kk + 4);
      fy0 = *(const float4*)(Bf1 + kk);
      fy1 = *(const float4*)(Bf1 + kk + 4);
    } else {
      rb0 = *(const uint4*)(Bh0 + kk);
      rb1 = *(const uint4*)(Bh1 + kk);
    }
  };
  auto store_tile = [&](int buf) {
    unsigned short* sa = sA + buf * 5120;
    unsigned short* sb = sB + buf * 5120;
    *(uint4*)(sa + wo0) = ra0;
    *(uint4*)(sa + wo1) = ra1;
    if (flag) {
      *(uint4*)(sb + wo0) = packbf(fx0, fx1);   // vmcnt wait lands here, 1 iter late
      *(uint4*)(sb + wo1) = packbf(fy0, fy1);
    } else {
      *(uint4*)(sb + wo0) = rb0;
      *(uint4*)(sb + wo1) = rb1;
    }
  };

  // preload: tile0 -> slot0; tile1 -> regs
  load_tile(0);
  store_tile(0);
  if (nt > 1) load_tile(32);
  BAR();

  const int fr = lane & 15, fc = (lane >> 4) * 8;
  floatx4 acc[4][4] = {};
  for (int t = 0; t < nt; ++t) {
    const unsigned short* as = sA + (t & 1) * 5120;
    const unsigned short* bs = sB + (t & 1) * 5120;
    short8 af[4], bfr[4];
    #pragma unroll
    for (int i = 0; i < 4; ++i) {
      af[i]  = *(const short8*)(as + (wm + i * 16 + fr) * 40 + fc);
      bfr[i] = *(const short8*)(bs + (wn + i * 16 + fr) * 40 + fc);
    }
    #pragma unroll
    for (int mi = 0; mi < 4; ++mi)
      #pragma unroll
      for (int ni = 0; ni < 4; ++ni)
        acc[mi][ni] = __builtin_amdgcn_mfma_f32_16x16x32_bf16(af[mi], bfr[ni], acc[mi][ni], 0, 0, 0);
    if (t + 1 < nt) {
      BAR();                                   // waves done reading slot (t+1)&1
      __builtin_amdgcn_sched_barrier(0);       // keep pack BELOW the compute phase
      store_tile((t + 1) & 1);                 // counted vmcnt: regs loaded 1 iter ago
      if (t + 2 < nt) load_tile((t + 2) * 32); // stays in flight across next BAR
      BAR();
    }
  }

  const void* bias = g.bias[d];
  const void* res = g.res[d];
  void* C = g.C[d];
  const size_t oo = g.oo[d];
  const bool first = (SPLITK <= 1) || (blockIdx.z == 0) || !flag;
  #pragma unroll
  for (int mi = 0; mi < 4; ++mi)
    #pragma unroll
    for (int ni = 0; ni < 4; ++ni)
      #pragma unroll
      for (int r = 0; r < 4; ++r) {
        int row = m0 + wm + mi * 16 + (lane >> 4) * 4 + r;
        int col = n0 + wn + ni * 16 + (lane & 15);
        float val = acc[mi][ni][r];
        size_t off = (size_t)row * N + col;
        if (first) {
          if (bias) val += loadE(bias, (size_t)col, flag);
          if (RES_MODE == 1) val += loadE(res, off, flag);
          if (RES_MODE == 3) {
            float h1v = bf2f(((const unsigned short*)res)[off]);
            val = (h1v / (1.0f + __expf(-h1v))) * val;
          }
          if (RES_MODE == 4) val += bf2f(((const unsigned short*)res)[off]);
        }
        if (OUT_MODE == 0) {
          ((unsigned short*)C)[off] = f2bf(val);
        } else {
          if (flag) {
            if (SPLITK > 1) atomicAdd((float*)C + oo + off, val);
            else            ((float*)C)[oo + off] = val;
          } else {
            ((unsigned short*)C)[oo + off] = f2bf(val);
          }
        }
      }
}

// ---------- per-(t,head) RMSNorm + RoPE, 4 heads/block, in place ----------
__global__ __launch_bounds__(256) void rmsrope_kernel(
    unsigned short* __restrict__ qk,
    const void* __restrict__ qn_c, const void* __restrict__ kn_c,
    const void* __restrict__ qn_x, const void* __restrict__ kn_x,
    const void* __restrict__ freqs, const int* __restrict__ flagp) {
  const int flag = *flagp;
  int t = blockIdx.x;
  int h = blockIdx.y * 4 + (threadIdx.x >> 6);
  int d = threadIdx.x & 63;
  unsigned short* qrow = qk + (size_t)t * 2048 + h * 64;
  unsigned short* krow = qrow + 1024;
  float q = bf2f(qrow[d]), k = bf2f(krow[d]);
  float qs = q * q, ks = k * k;
  for (int off = 32; off; off >>= 1) {
    qs += __shfl_xor(qs, off, 64);
    ks += __shfl_xor(ks, off, 64);
  }
  const void* qn = (t < 512) ? qn_c : qn_x;
  const void* kn = (t < 512) ? kn_c : kn_x;
  q = q * rsqrtf(qs * (1.0f / 64.0f) + 1e-6f) * loadE(qn, d, flag);
  k = k * rsqrtf(ks * (1.0f / 64.0f) + 1e-6f) * loadE(kn, d, flag);
  int j = d >> 1;
  float cv = loadE(freqs, (size_t)(t * 32 + j) * 2 + 0, flag);
  float sv = loadE(freqs, (size_t)(t * 32 + j) * 2 + 1, flag);
  float qo = __shfl_xor(q, 1, 64);
  float ko = __shfl_xor(k, 1, 64);
  float qn2, kn2;
  if ((d & 1) == 0) { qn2 = q * cv - qo * sv; kn2 = k * cv - ko * sv; }
  else              { qn2 = qo * sv + q * cv; kn2 = ko * sv + k * cv; }
  qrow[d] = f2bf(qn2);
  krow[d] = f2bf(kn2);
}

// ---------- MFMA flash attention: 64 Q-rows/block (4 waves x 16), 64-key tiles ----------
__global__ __launch_bounds__(256) void attn_kernel(const unsigned short* __restrict__ qk,
                                                   const unsigned short* __restrict__ v,
                                                   unsigned short* __restrict__ y) {
  int id = blockIdx.x;
  int blk = (id & 256) ? (31 - (id & 31)) : (id & 31);
  int h = (id >> 5) & 15;
  int wv = threadIdx.x >> 6;
  int lane = threadIdx.x & 63;
  int qbase = blk * 64 + wv * 16;

  __shared__ __align__(16) unsigned short Ks[64 * 72];
  __shared__ __align__(16) unsigned short Vt[64 * 64];
  __shared__ __align__(16) unsigned short ps[4][16 * 72];

  short8 qa[2];
  {
    int m = lane & 15, dj = (lane >> 4) * 8;
    const unsigned short* qp = qk + (size_t)(qbase + m) * 2048 + h * 64 + dj;
    qa[0] = *(const short8*)(qp);
    qa[1] = *(const short8*)(qp + 32);
  }
  floatx4 o[4] = {};
  float mrow[4] = {-1e30f, -1e30f, -1e30f, -1e30f};
  float lrow[4] = {0.f, 0.f, 0.f, 0.f};
  int ntiles = blk + 1;
  for (int tile = 0; tile < ntiles; ++tile) {
    int j0 = tile * 64;
    __syncthreads();
    for (int c2 = threadIdx.x; c2 < 512; c2 += 256) {
      int key = c2 >> 3, d0 = (c2 & 7) * 8;
      *(short8*)(Ks + key * 72 + d0) =
          *(const short8*)(qk + (size_t)(j0 + key) * 2048 + 1024 + h * 64 + d0);
      short8 vv = *(const short8*)(v + (size_t)(j0 + key) * 1024 + h * 64 + d0);
      int bphys = ((key >> 3) ^ (d0 >> 3)) * 8 + (key & 7);
      #pragma unroll
      for (int jj = 0; jj < 8; ++jj)
        Vt[(d0 + jj) * 64 + bphys] = ((const unsigned short*)&vv)[jj];
    }
    __syncthreads();
    floatx4 sacc[4];
    #pragma unroll
    for (int kg = 0; kg < 4; ++kg) {
      floatx4 z = {0.f, 0.f, 0.f, 0.f};
      #pragma unroll
      for (int kc = 0; kc < 2; ++kc) {
        short8 kb = *(const short8*)(Ks + (kg * 16 + (lane & 15)) * 72 + kc * 32 + (lane >> 4) * 8);
        z = __builtin_amdgcn_mfma_f32_16x16x32_bf16(qa[kc], kb, z, 0, 0, 0);
      }
      sacc[kg] = z;
    }
    #pragma unroll
    for (int kg = 0; kg < 4; ++kg)
      #pragma unroll
      for (int r = 0; r < 4; ++r) {
        int key_g = j0 + kg * 16 + (lane & 15);
        int q_g = qbase + (lane >> 4) * 4 + r;
        float s = sacc[kg][r] * 0.125f;
        sacc[kg][r] = (key_g <= q_g) ? s : -1e30f;
      }
    #pragma unroll
    for (int r = 0; r < 4; ++r) {
      float mx = fmaxf(fmaxf(sacc[0][r], sacc[1][r]), fmaxf(sacc[2][r], sacc[3][r]));
      mx = fmaxf(mx, __shfl_xor(mx, 1, 64));
      mx = fmaxf(mx, __shfl_xor(mx, 2, 64));
      mx = fmaxf(mx, __shfl_xor(mx, 4, 64));
      mx = fmaxf(mx, __shfl_xor(mx, 8, 64));
      float mnew = fmaxf(mrow[r], mx);
      float al = __expf(mrow[r] - mnew);
      mrow[r] = mnew;
      float sum = 0.f;
      #pragma unroll
      for (int kg = 0; kg < 4; ++kg) {
        float p = __expf(sacc[kg][r] - mnew);
        sacc[kg][r] = p;
        sum += p;
      }
      sum += __shfl_xor(sum, 1, 64);
      sum += __shfl_xor(sum, 2, 64);
      sum += __shfl_xor(sum, 4, 64);
      sum += __shfl_xor(sum, 8, 64);
      lrow[r] = lrow[r] * al + sum;
      #pragma unroll
      for (int ni = 0; ni < 4; ++ni) o[ni][r] *= al;
    }
    unsigned short* pw = ps[wv];
    #pragma unroll
    for (int kg = 0; kg < 4; ++kg)
      #pragma unroll
      for (int r = 0; r < 4; ++r)
        pw[((lane >> 4) * 4 + r) * 72 + kg * 16 + (lane & 15)] = f2bf(sacc[kg][r]);
    asm volatile("s_waitcnt lgkmcnt(0)" ::: "memory");
    short8 pa[2];
    pa[0] = *(const short8*)(pw + (lane & 15) * 72 + (lane >> 4) * 8);
    pa[1] = *(const short8*)(pw + (lane & 15) * 72 + 32 + (lane >> 4) * 8);
    #pragma unroll
    for (int ni = 0; ni < 4; ++ni) {
      floatx4 z = o[ni];
      int dd = ni * 16 + (lane & 15);
      #pragma unroll
      for (int kc = 0; kc < 2; ++kc) {
        int bphys = (kc * 4 + (lane >> 4)) ^ (dd >> 3);
        short8 vb = *(const short8*)(Vt + dd * 64 + bphys * 8);
        z = __builtin_amdgcn_mfma_f32_16x16x32_bf16(pa[kc], vb, z, 0, 0, 0);
      }
      o[ni] = z;
    }
  }
  #pragma unroll
  for (int ni = 0; ni < 4; ++ni)
    #pragma unroll
    for (int r = 0; r < 4; ++r) {
      int q = qbase + (lane >> 4) * 4 + r;
      int dd = ni * 16 + (lane & 15);
      y[(size_t)q * 1024 + h * 64 + dd] = f2bf(o[ni][r] / lrow[r]);
    }
}

extern "C" void kernel_launch(void* const* d_in, const int* in_sizes, int n_in,
                              void* d_out, int out_size, void* d_ws, size_t ws_size,
                              hipStream_t stream) {
  const int L = 1536, S = 512, D = 1024, T = 2048, FF = 4096;
  const void* x        = d_in[0];
  const void* c        = d_in[1];
  const void* freqs    = d_in[2];
  const void* px_qk_w  = d_in[3];
  const void* px_qn    = d_in[4];
  const void* px_kn    = d_in[5];
  const void* px_v_w   = d_in[6];
  const void* px_v_b   = d_in[7];
  const void* pc_qk_w  = d_in[8];
  const void* pc_qn    = d_in[9];
  const void* pc_kn    = d_in[10];
  const void* pc_v_w   = d_in[11];
  const void* pc_v_b   = d_in[12];
  const void* p1_proj_w = d_in[13];
  const void* p1_proj_b = d_in[14];
  const void* p1_w1 = d_in[15];
  const void* p1_b1 = d_in[16];
  const void* p1_w3 = d_in[17];
  const void* p1_b3 = d_in[18];
  const void* p1_w2 = d_in[19];
  const void* p1_b2 = d_in[20];
  const void* p2_proj_w = d_in[21];
  const void* p2_proj_b = d_in[22];
  const void* p2_w1 = d_in[23];
  const void* p2_b1 = d_in[24];
  const void* p2_w3 = d_in[25];
  const void* p2_b3 = d_in[26];
  const void* p2_w2 = d_in[27];
  const void* p2_b2 = d_in[28];

  // Workspace (21 MB + flag):
  //  [0,4)   hln -> ybuf (attn out) -> h1c (c-stream MLP hidden, 4 MiB)
  //  [4,12)  qk [T][2048]           -> (dead after attn)
  //  [12,16) v  [T][D]              -> (dead after attn)
  //  [4,16)  h1x (x-stream MLP hidden, exactly 12 MiB)
  //  [16,20) mid [T][D] bf16 (live to W2)
  //  [20,21) midln_c
  //  [21MB]  dtype flag
  //  midln_x = d_out[0,3MiB) scratch (consumed by W1/W3 before d_out is zeroed)
  char* ws = (char*)d_ws;
  unsigned short* hln     = (unsigned short*)(ws);
  unsigned short* ybuf    = (unsigned short*)(ws);
  unsigned short* h1c     = (unsigned short*)(ws);
  unsigned short* qkbuf   = (unsigned short*)(ws + ((size_t)4  << 20));
  unsigned short* h1x     = (unsigned short*)(ws + ((size_t)4  << 20));
  unsigned short* vbuf    = (unsigned short*)(ws + ((size_t)12 << 20));
  unsigned short* mid     = (unsigned short*)(ws + ((size_t)16 << 20));
  unsigned short* midln_c = (unsigned short*)(ws + ((size_t)20 << 20));
  int*            flag    = (int*)(ws + ((size_t)21 << 20));
  unsigned short* midln_x = (unsigned short*)d_out;
  unsigned short* hlnx    = hln + (size_t)S * D;

  detect_kernel<<<1, 64, 0, stream>>>((const unsigned int*)px_qn, flag);
  ln_ext_kernel<<<T, 256, 0, stream>>>(c, x, hln, flag);

  // P1: QKV (4 descriptors, one dispatch)
  {
    GArgs g = {};
    g.A[0] = hln;  g.B[0] = pc_qk_w; g.bias[0] = nullptr; g.C[0] = qkbuf;                    g.mcum[0] = 4;  g.N[0] = 2048;
    g.A[1] = hlnx; g.B[1] = px_qk_w; g.bias[1] = nullptr; g.C[1] = qkbuf + (size_t)S * 2048; g.mcum[1] = 16; g.N[1] = 2048;
    g.A[2] = hln;  g.B[2] = pc_v_w;  g.bias[2] = pc_v_b;  g.C[2] = vbuf;                     g.mcum[2] = 20; g.N[2] = 1024;
    g.A[3] = hlnx; g.B[3] = px_v_w;  g.bias[3] = px_v_b;  g.C[3] = vbuf + (size_t)S * D;     g.mcum[3] = 32; g.N[3] = 1024;
    g.K = 1024; g.nd = 4;
    gemm_kernel<0, 0, 1><<<dim3(16, 32), 256, 0, stream>>>(g, flag);
  }
  rmsrope_kernel<<<dim3(T, 4), 256, 0, stream>>>(qkbuf, pc_qn, pc_kn, px_qn, px_kn, freqs, flag);
  attn_kernel<<<512, 256, 0, stream>>>(qkbuf, vbuf, ybuf);

  // P2: out-projection + external residual -> mid
  {
    GArgs g = {};
    g.A[0] = ybuf;                  g.B[0] = p2_proj_w; g.bias[0] = p2_proj_b; g.res[0] = c; g.C[0] = mid;                  g.mcum[0] = 4;  g.N[0] = 1024;
    g.A[1] = ybuf + (size_t)S * D;  g.B[1] = p1_proj_w; g.bias[1] = p1_proj_b; g.res[1] = x; g.C[1] = mid + (size_t)S * D;  g.mcum[1] = 16; g.N[1] = 1024;
    g.K = 1024; g.nd = 2;
    gemm_kernel<1, 0, 1><<<dim3(8, 16), 256, 0, stream>>>(g, flag);
  }
  ln_mid_kernel<<<T, 256, 0, stream>>>(mid, midln_c, midln_x);

  // P3: W1 (x + c merged)
  {
    GArgs g = {};
    g.A[0] = midln_x; g.B[0] = p1_w1; g.bias[0] = p1_b1; g.C[0] = h1x; g.mcum[0] = 12; g.N[0] = 4096;
    g.A[1] = midln_c; g.B[1] = p2_w1; g.bias[1] = p2_b1; g.C[1] = h1c; g.mcum[1] = 16; g.N[1] = 4096;
    g.K = 1024; g.nd = 2;
    gemm_kernel<0, 0, 1><<<dim3(32, 16), 256, 0, stream>>>(g, flag);
  }
  // P4: W3 with fused silu(h1)*(acc+bias), in place
  {
    GArgs g = {};
    g.A[0] = midln_x; g.B[0] = p1_w3; g.bias[0] = p1_b3; g.res[0] = h1x; g.C[0] = h1x; g.mcum[0] = 12; g.N[0] = 4096;
    g.A[1] = midln_c; g.B[1] = p2_w3; g.bias[1] = p2_b3; g.res[1] = h1c; g.C[1] = h1c; g.mcum[1] = 16; g.N[1] = 4096;
    g.K = 1024; g.nd = 2;
    gemm_kernel<3, 0, 1><<<dim3(32, 16), 256, 0, stream>>>(g, flag);
  }
  // zero d_out, then P5: W2 split-K=8 atomics (+bias+res by slice 0)
  zero_kernel<<<2048, 256, 0, stream>>>(d_out, out_size, flag);
  {
    GArgs g = {};
    g.A[0] = h1x; g.B[0] = p1_w2; g.bias[0] = p1_b2; g.res[0] = mid + (size_t)S * D; g.C[0] = d_out; g.oo[0] = 0;             g.mcum[0] = 12; g.N[0] = 1024;
    g.A[1] = h1c; g.B[1] = p2_w2; g.bias[1] = p2_b2; g.res[1] = mid;                 g.C[1] = d_out; g.oo[1] = (size_t)L * D; g.mcum[1] = 16; g.N[1] = 1024;
    g.K = 4096; g.nd = 2;
    gemm_kernel<4, 2, 8><<<dim3(8, 16, 8), 256, 0, stream>>>(g, flag);
  }
}

// Round 4
// 531.954 us; speedup vs baseline: 1.2617x; 1.2617x over previous
//
#include <hip/hip_runtime.h>

typedef __attribute__((ext_vector_type(8))) short short8;
typedef __attribute__((ext_vector_type(4))) float floatx4;

// ---------- bf16 helpers ----------
__device__ __forceinline__ float bf2f(unsigned short u) {
  union { unsigned int i; float f; } v; v.i = ((unsigned int)u) << 16; return v.f;
}
__device__ __forceinline__ unsigned short f2bf(float f) {
  union { float f; unsigned int i; } v; v.f = f;
  unsigned int x = v.i + 0x7fffu + ((v.i >> 16) & 1u);
  return (unsigned short)(x >> 16);
}
__device__ __forceinline__ float loadE(const void* p, size_t i, int f) {
  return f ? ((const float*)p)[i] : bf2f(((const unsigned short*)p)[i]);
}
__device__ __forceinline__ uint4 packbf(float4 a, float4 b) {
  union { unsigned short u[8]; uint4 v; } p;
  p.u[0] = f2bf(a.x); p.u[1] = f2bf(a.y); p.u[2] = f2bf(a.z); p.u[3] = f2bf(a.w);
  p.u[4] = f2bf(b.x); p.u[5] = f2bf(b.y); p.u[6] = f2bf(b.z); p.u[7] = f2bf(b.w);
  return p.v;
}

// ---------- dtype detect ----------
__global__ void detect_kernel(const unsigned int* __restrict__ probe, int* __restrict__ flag) {
  if (threadIdx.x == 0 && blockIdx.x == 0) *flag = (probe[0] == 0x3F800000u) ? 1 : 0;
}

// ---------- one-shot weight conversion: all 12 weight matrices -> bf16 ----------
// Hoists the fp32->bf16 pack OUT of every GEMM K-loop (rounds 0-2 showed the pack
// in the hot loop either stalls at load-issue or defeats the scheduler when deferred).
// 134 MB read + 64 MB write, memory-bound, ~35us once per launch.
struct CArgs {
  const void* in[12];
  unsigned short* out[12];
  unsigned int cum[12];  // cumulative chunk (8-elem) counts
};
__global__ __launch_bounds__(256) void convw_kernel(CArgs a, int total_chunks,
                                                    const int* __restrict__ flagp) {
  const int flag = *flagp;
  for (int c = blockIdx.x * 256 + threadIdx.x; c < total_chunks; c += gridDim.x * 256) {
    int s = 0;
    while (c >= (int)a.cum[s]) ++s;
    unsigned int base = s ? a.cum[s - 1] : 0u;
    size_t e = (size_t)(c - base) * 8;
    if (flag) {
      const float* in = (const float*)a.in[s] + e;
      float4 v0 = *(const float4*)in;
      float4 v1 = *(const float4*)(in + 4);
      *(uint4*)(a.out[s] + e) = packbf(v0, v1);
    } else {
      *(uint4*)(a.out[s] + e) = *(const uint4*)((const unsigned short*)a.in[s] + e);
    }
  }
}

// ---------- zero d_out (dtype-aware) ----------
__global__ __launch_bounds__(256) void zero_kernel(void* __restrict__ out, int out_elems,
                                                   const int* __restrict__ flagp) {
  int limit = (*flagp) ? (out_elems >> 2) : (out_elems >> 3);  // uint4 chunks
  int i = blockIdx.x * 256 + threadIdx.x;
  if (i < limit) ((uint4*)out)[i] = make_uint4(0, 0, 0, 0);
}

// ---------- LayerNorm over both external inputs -> unified bf16 (c rows first) ----------
__global__ __launch_bounds__(256) void ln_ext_kernel(const void* __restrict__ cin,
                                                     const void* __restrict__ xin,
                                                     unsigned short* __restrict__ out,
                                                     const int* __restrict__ flagp) {
  const int D = 1024, S = 512;
  const int flag = *flagp;
  int row = blockIdx.x;
  const void* src = (row < S) ? cin : xin;
  size_t rb = (size_t)(row < S ? row : row - S) * D;
  int base = threadIdx.x * 4;
  float x0 = loadE(src, rb + base + 0, flag);
  float x1 = loadE(src, rb + base + 1, flag);
  float x2 = loadE(src, rb + base + 2, flag);
  float x3 = loadE(src, rb + base + 3, flag);
  float s1 = x0 + x1 + x2 + x3;
  float s2 = x0 * x0 + x1 * x1 + x2 * x2 + x3 * x3;
  for (int off = 32; off; off >>= 1) {
    s1 += __shfl_down(s1, off, 64);
    s2 += __shfl_down(s2, off, 64);
  }
  __shared__ float red[8];
  int wid = threadIdx.x >> 6;
  if ((threadIdx.x & 63) == 0) { red[wid] = s1; red[4 + wid] = s2; }
  __syncthreads();
  s1 = red[0] + red[1] + red[2] + red[3];
  s2 = red[4] + red[5] + red[6] + red[7];
  float mean = s1 * (1.0f / D);
  float var = s2 * (1.0f / D) - mean * mean;
  float inv = rsqrtf(var + 1e-6f);
  unsigned short* dst = out + (size_t)row * D + base;
  dst[0] = f2bf((x0 - mean) * inv);
  dst[1] = f2bf((x1 - mean) * inv);
  dst[2] = f2bf((x2 - mean) * inv);
  dst[3] = f2bf((x3 - mean) * inv);
}

// ---------- LayerNorm over internal bf16 mid; split outputs ----------
__global__ __launch_bounds__(256) void ln_mid_kernel(const unsigned short* __restrict__ in,
                                                     unsigned short* __restrict__ outc,
                                                     unsigned short* __restrict__ outx) {
  const int D = 1024, S = 512;
  int row = blockIdx.x;
  const unsigned short* src = in + (size_t)row * D;
  int base = threadIdx.x * 4;
  float x0 = bf2f(src[base + 0]);
  float x1 = bf2f(src[base + 1]);
  float x2 = bf2f(src[base + 2]);
  float x3 = bf2f(src[base + 3]);
  float s1 = x0 + x1 + x2 + x3;
  float s2 = x0 * x0 + x1 * x1 + x2 * x2 + x3 * x3;
  for (int off = 32; off; off >>= 1) {
    s1 += __shfl_down(s1, off, 64);
    s2 += __shfl_down(s2, off, 64);
  }
  __shared__ float red[8];
  int wid = threadIdx.x >> 6;
  if ((threadIdx.x & 63) == 0) { red[wid] = s1; red[4 + wid] = s2; }
  __syncthreads();
  s1 = red[0] + red[1] + red[2] + red[3];
  s2 = red[4] + red[5] + red[6] + red[7];
  float mean = s1 * (1.0f / D);
  float var = s2 * (1.0f / D) - mean * mean;
  float inv = rsqrtf(var + 1e-6f);
  unsigned short* dst = (row < S ? outc + (size_t)row * D : outx + (size_t)(row - S) * D) + base;
  dst[0] = f2bf((x0 - mean) * inv);
  dst[1] = f2bf((x1 - mean) * inv);
  dst[2] = f2bf((x2 - mean) * inv);
  dst[3] = f2bf((x3 - mean) * inv);
}

// ---------- multi-descriptor GEMM ----------
// C[M,N] = A[M,K](bf16) @ B[N,K]^T. 128x128 tile, BK=32, 4 waves, 4x4 mfma,
// LDS double-buffer (pad 40 hw).
// BBF16=1 (workspace-converted weights): B is bf16, staging is pure uint4 loads,
// ONE lgkm-only barrier per tile, store at TOP of iteration (into the buffer the
// previous barrier freed), then issue tile t+2 loads BEFORE compute -> loads span
// the full compute phase before consumption (T3/T4 counted-wait principle; the
// vmcnt wait at next iter's store is fully covered).
// BBF16=0 fallback (workspace too small): round-1 dual-dtype path (pack at load).
// RES_MODE: 0 none, 1 += external dual res, 3 out=silu(bf16 res)*(acc+bias), 4 += bf16 res.
// OUT_MODE: 0 internal bf16, 2 external dual. SPLITK>1 (OUT 2 only): fp32 atomicAdd slices
// (bias/res added by slice 0); bf16-out fallback: slice 0 does full K, others exit.
struct GArgs {
  const unsigned short* A[4];
  const void* B[4];
  const void* bias[4];
  const void* res[4];
  void* C[4];
  unsigned long long oo[4];
  int mcum[4];  // cumulative m-tile counts
  int N[4];
  int K;
  int nd;
};

// LDS-only fence + barrier: drains this wave's ds reads/writes, NOT vmcnt, so
// in-flight global prefetch survives the barrier.
#define BAR() asm volatile("s_waitcnt lgkmcnt(0)\n\ts_barrier" ::: "memory")

template <int RES_MODE, int OUT_MODE, int SPLITK, int BBF16>
__global__ __launch_bounds__(256) void gemm_kernel(GArgs g, const int* __restrict__ flagp) {
  const int flag = *flagp;
  // descriptor select
  int by = blockIdx.y;
  int d = 0;
  while (d < g.nd - 1 && by >= g.mcum[d]) ++d;
  int mbase = (d == 0) ? 0 : g.mcum[d - 1];
  const int m0 = (by - mbase) * 128;
  const int N = g.N[d];
  const int n0 = blockIdx.x * 128;
  if (n0 >= N) return;  // block-uniform
  const int K = g.K;
  // K slice
  int kbeg = 0, kend = K;
  if (SPLITK > 1) {
    if (!flag) {
      if (blockIdx.z != 0) return;
    } else {
      int kl = K / SPLITK;
      kbeg = blockIdx.z * kl;
      kend = kbeg + kl;
    }
  }
  const int nt = (kend - kbeg) >> 5;

  __shared__ __align__(16) unsigned short sA[2 * 5120];  // 128 rows x 40 hw, 2 buffers
  __shared__ __align__(16) unsigned short sB[2 * 5120];

  const int tid = threadIdx.x;
  const int lane = tid & 63;
  const int wave = tid >> 6;
  const int wm = (wave >> 1) * 64, wn = (wave & 1) * 64;
  // staging assignment: chunk c in {tid, tid+256}; row=c>>2 (0..127), colblk=c&3 (8 hw)
  const int srow = tid >> 2;
  const int scol = (tid & 3) * 8;
  const int wo0 = srow * 40 + scol;
  const int wo1 = wo0 + 64 * 40;
  const unsigned short* Ag0 = g.A[d] + (size_t)(m0 + srow) * K + kbeg + scol;
  const unsigned short* Ag1 = Ag0 + (size_t)64 * K;
  const unsigned short* Bh0 = (const unsigned short*)g.B[d] + (size_t)(n0 + srow) * K + kbeg + scol;
  const unsigned short* Bh1 = Bh0 + (size_t)64 * K;
  const float* Bf0 = (const float*)g.B[d] + (size_t)(n0 + srow) * K + kbeg + scol;
  const float* Bf1 = Bf0 + (size_t)64 * K;

  uint4 ra0, ra1, rb0, rb1;
  auto load_tile = [&](int kk) {
    ra0 = *(const uint4*)(Ag0 + kk);
    ra1 = *(const uint4*)(Ag1 + kk);
    if (BBF16 || !flag) {
      rb0 = *(const uint4*)(Bh0 + kk);
      rb1 = *(const uint4*)(Bh1 + kk);
    } else {
      float4 x0 = *(const float4*)(Bf0 + kk), x1 = *(const float4*)(Bf0 + kk + 4);
      float4 y0 = *(const float4*)(Bf1 + kk), y1 = *(const float4*)(Bf1 + kk + 4);
      rb0 = packbf(x0, x1);
      rb1 = packbf(y0, y1);
    }
  };
  auto store_tile = [&](int buf) {
    unsigned short* sa = sA + buf * 5120;
    unsigned short* sb = sB + buf * 5120;
    *(uint4*)(sa + wo0) = ra0;
    *(uint4*)(sa + wo1) = ra1;
    *(uint4*)(sb + wo0) = rb0;
    *(uint4*)(sb + wo1) = rb1;
  };

  // preload: tile0 -> slot0; tile1 -> regs
  load_tile(0);
  store_tile(0);
  if (nt > 1) load_tile(32);
  BAR();

  const int fr = lane & 15, fc = (lane >> 4) * 8;
  floatx4 acc[4][4] = {};
  for (int t = 0; t < nt; ++t) {
    // store tile t+1 into the buffer freed by the previous barrier, then issue
    // tile t+2 loads so they fly across the whole compute phase below.
    if (t + 1 < nt) {
      store_tile((t + 1) & 1);
      if (t + 2 < nt) load_tile((t + 2) * 32);
    }
    const unsigned short* as = sA + (t & 1) * 5120;
    const unsigned short* bs = sB + (t & 1) * 5120;
    short8 af[4], bfr[4];
    #pragma unroll
    for (int i = 0; i < 4; ++i) {
      af[i]  = *(const short8*)(as + (wm + i * 16 + fr) * 40 + fc);
      bfr[i] = *(const short8*)(bs + (wn + i * 16 + fr) * 40 + fc);
    }
    #pragma unroll
    for (int mi = 0; mi < 4; ++mi)
      #pragma unroll
      for (int ni = 0; ni < 4; ++ni)
        acc[mi][ni] = __builtin_amdgcn_mfma_f32_16x16x32_bf16(af[mi], bfr[ni], acc[mi][ni], 0, 0, 0);
    if (t + 1 < nt) BAR();  // writes visible + all waves done reading buf[t&1]
  }

  const void* bias = g.bias[d];
  const void* res = g.res[d];
  void* C = g.C[d];
  const size_t oo = g.oo[d];
  const bool first = (SPLITK <= 1) || (blockIdx.z == 0) || !flag;
  #pragma unroll
  for (int mi = 0; mi < 4; ++mi)
    #pragma unroll
    for (int ni = 0; ni < 4; ++ni)
      #pragma unroll
      for (int r = 0; r < 4; ++r) {
        int row = m0 + wm + mi * 16 + (lane >> 4) * 4 + r;
        int col = n0 + wn + ni * 16 + (lane & 15);
        float val = acc[mi][ni][r];
        size_t off = (size_t)row * N + col;
        if (first) {
          if (bias) val += loadE(bias, (size_t)col, flag);
          if (RES_MODE == 1) val += loadE(res, off, flag);
          if (RES_MODE == 3) {
            float h1v = bf2f(((const unsigned short*)res)[off]);
            val = (h1v / (1.0f + __expf(-h1v))) * val;
          }
          if (RES_MODE == 4) val += bf2f(((const unsigned short*)res)[off]);
        }
        if (OUT_MODE == 0) {
          ((unsigned short*)C)[off] = f2bf(val);
        } else {
          if (flag) {
            if (SPLITK > 1) atomicAdd((float*)C + oo + off, val);
            else            ((float*)C)[oo + off] = val;
          } else {
            ((unsigned short*)C)[oo + off] = f2bf(val);
          }
        }
      }
}

// ---------- per-(t,head) RMSNorm + RoPE, 4 heads/block, in place ----------
__global__ __launch_bounds__(256) void rmsrope_kernel(
    unsigned short* __restrict__ qk,
    const void* __restrict__ qn_c, const void* __restrict__ kn_c,
    const void* __restrict__ qn_x, const void* __restrict__ kn_x,
    const void* __restrict__ freqs, const int* __restrict__ flagp) {
  const int flag = *flagp;
  int t = blockIdx.x;
  int h = blockIdx.y * 4 + (threadIdx.x >> 6);
  int d = threadIdx.x & 63;
  unsigned short* qrow = qk + (size_t)t * 2048 + h * 64;
  unsigned short* krow = qrow + 1024;
  float q = bf2f(qrow[d]), k = bf2f(krow[d]);
  float qs = q * q, ks = k * k;
  for (int off = 32; off; off >>= 1) {
    qs += __shfl_xor(qs, off, 64);
    ks += __shfl_xor(ks, off, 64);
  }
  const void* qn = (t < 512) ? qn_c : qn_x;
  const void* kn = (t < 512) ? kn_c : kn_x;
  q = q * rsqrtf(qs * (1.0f / 64.0f) + 1e-6f) * loadE(qn, d, flag);
  k = k * rsqrtf(ks * (1.0f / 64.0f) + 1e-6f) * loadE(kn, d, flag);
  int j = d >> 1;
  float cv = loadE(freqs, (size_t)(t * 32 + j) * 2 + 0, flag);
  float sv = loadE(freqs, (size_t)(t * 32 + j) * 2 + 1, flag);
  float qo = __shfl_xor(q, 1, 64);
  float ko = __shfl_xor(k, 1, 64);
  float qn2, kn2;
  if ((d & 1) == 0) { qn2 = q * cv - qo * sv; kn2 = k * cv - ko * sv; }
  else              { qn2 = qo * sv + q * cv; kn2 = ko * sv + k * cv; }
  qrow[d] = f2bf(qn2);
  krow[d] = f2bf(kn2);
}

// ---------- MFMA flash attention: 64 Q-rows/block (4 waves x 16), 64-key tiles ----------
__global__ __launch_bounds__(256) void attn_kernel(const unsigned short* __restrict__ qk,
                                                   const unsigned short* __restrict__ v,
                                                   unsigned short* __restrict__ y) {
  int id = blockIdx.x;
  int blk = (id & 256) ? (31 - (id & 31)) : (id & 31);
  int h = (id >> 5) & 15;
  int wv = threadIdx.x >> 6;
  int lane = threadIdx.x & 63;
  int qbase = blk * 64 + wv * 16;

  __shared__ __align__(16) unsigned short Ks[64 * 72];
  __shared__ __align__(16) unsigned short Vt[64 * 64];
  __shared__ __align__(16) unsigned short ps[4][16 * 72];

  short8 qa[2];
  {
    int m = lane & 15, dj = (lane >> 4) * 8;
    const unsigned short* qp = qk + (size_t)(qbase + m) * 2048 + h * 64 + dj;
    qa[0] = *(const short8*)(qp);
    qa[1] = *(const short8*)(qp + 32);
  }
  floatx4 o[4] = {};
  float mrow[4] = {-1e30f, -1e30f, -1e30f, -1e30f};
  float lrow[4] = {0.f, 0.f, 0.f, 0.f};
  int ntiles = blk + 1;
  for (int tile = 0; tile < ntiles; ++tile) {
    int j0 = tile * 64;
    __syncthreads();
    for (int c2 = threadIdx.x; c2 < 512; c2 += 256) {
      int key = c2 >> 3, d0 = (c2 & 7) * 8;
      *(short8*)(Ks + key * 72 + d0) =
          *(const short8*)(qk + (size_t)(j0 + key) * 2048 + 1024 + h * 64 + d0);
      short8 vv = *(const short8*)(v + (size_t)(j0 + key) * 1024 + h * 64 + d0);
      int bphys = ((key >> 3) ^ (d0 >> 3)) * 8 + (key & 7);
      #pragma unroll
      for (int jj = 0; jj < 8; ++jj)
        Vt[(d0 + jj) * 64 + bphys] = ((const unsigned short*)&vv)[jj];
    }
    __syncthreads();
    floatx4 sacc[4];
    #pragma unroll
    for (int kg = 0; kg < 4; ++kg) {
      floatx4 z = {0.f, 0.f, 0.f, 0.f};
      #pragma unroll
      for (int kc = 0; kc < 2; ++kc) {
        short8 kb = *(const short8*)(Ks + (kg * 16 + (lane & 15)) * 72 + kc * 32 + (lane >> 4) * 8);
        z = __builtin_amdgcn_mfma_f32_16x16x32_bf16(qa[kc], kb, z, 0, 0, 0);
      }
      sacc[kg] = z;
    }
    #pragma unroll
    for (int kg = 0; kg < 4; ++kg)
      #pragma unroll
      for (int r = 0; r < 4; ++r) {
        int key_g = j0 + kg * 16 + (lane & 15);
        int q_g = qbase + (lane >> 4) * 4 + r;
        float s = sacc[kg][r] * 0.125f;
        sacc[kg][r] = (key_g <= q_g) ? s : -1e30f;
      }
    #pragma unroll
    for (int r = 0; r < 4; ++r) {
      float mx = fmaxf(fmaxf(sacc[0][r], sacc[1][r]), fmaxf(sacc[2][r], sacc[3][r]));
      mx = fmaxf(mx, __shfl_xor(mx, 1, 64));
      mx = fmaxf(mx, __shfl_xor(mx, 2, 64));
      mx = fmaxf(mx, __shfl_xor(mx, 4, 64));
      mx = fmaxf(mx, __shfl_xor(mx, 8, 64));
      float mnew = fmaxf(mrow[r], mx);
      float al = __expf(mrow[r] - mnew);
      mrow[r] = mnew;
      float sum = 0.f;
      #pragma unroll
      for (int kg = 0; kg < 4; ++kg) {
        float p = __expf(sacc[kg][r] - mnew);
        sacc[kg][r] = p;
        sum += p;
      }
      sum += __shfl_xor(sum, 1, 64);
      sum += __shfl_xor(sum, 2, 64);
      sum += __shfl_xor(sum, 4, 64);
      sum += __shfl_xor(sum, 8, 64);
      lrow[r] = lrow[r] * al + sum;
      #pragma unroll
      for (int ni = 0; ni < 4; ++ni) o[ni][r] *= al;
    }
    unsigned short* pw = ps[wv];
    #pragma unroll
    for (int kg = 0; kg < 4; ++kg)
      #pragma unroll
      for (int r = 0; r < 4; ++r)
        pw[((lane >> 4) * 4 + r) * 72 + kg * 16 + (lane & 15)] = f2bf(sacc[kg][r]);
    asm volatile("s_waitcnt lgkmcnt(0)" ::: "memory");
    short8 pa[2];
    pa[0] = *(const short8*)(pw + (lane & 15) * 72 + (lane >> 4) * 8);
    pa[1] = *(const short8*)(pw + (lane & 15) * 72 + 32 + (lane >> 4) * 8);
    #pragma unroll
    for (int ni = 0; ni < 4; ++ni) {
      floatx4 z = o[ni];
      int dd = ni * 16 + (lane & 15);
      #pragma unroll
      for (int kc = 0; kc < 2; ++kc) {
        int bphys = (kc * 4 + (lane >> 4)) ^ (dd >> 3);
        short8 vb = *(const short8*)(Vt + dd * 64 + bphys * 8);
        z = __builtin_amdgcn_mfma_f32_16x16x32_bf16(pa[kc], vb, z, 0, 0, 0);
      }
      o[ni] = z;
    }
  }
  #pragma unroll
  for (int ni = 0; ni < 4; ++ni)
    #pragma unroll
    for (int r = 0; r < 4; ++r) {
      int q = qbase + (lane >> 4) * 4 + r;
      int dd = ni * 16 + (lane & 15);
      y[(size_t)q * 1024 + h * 64 + dd] = f2bf(o[ni][r] / lrow[r]);
    }
}

extern "C" void kernel_launch(void* const* d_in, const int* in_sizes, int n_in,
                              void* d_out, int out_size, void* d_ws, size_t ws_size,
                              hipStream_t stream) {
  const int L = 1536, S = 512, D = 1024, T = 2048, FF = 4096;
  const void* x        = d_in[0];
  const void* c        = d_in[1];
  const void* freqs    = d_in[2];
  const void* px_qk_w  = d_in[3];
  const void* px_qn    = d_in[4];
  const void* px_kn    = d_in[5];
  const void* px_v_w   = d_in[6];
  const void* px_v_b   = d_in[7];
  const void* pc_qk_w  = d_in[8];
  const void* pc_qn    = d_in[9];
  const void* pc_kn    = d_in[10];
  const void* pc_v_w   = d_in[11];
  const void* pc_v_b   = d_in[12];
  const void* p1_proj_w = d_in[13];
  const void* p1_proj_b = d_in[14];
  const void* p1_w1 = d_in[15];
  const void* p1_b1 = d_in[16];
  const void* p1_w3 = d_in[17];
  const void* p1_b3 = d_in[18];
  const void* p1_w2 = d_in[19];
  const void* p1_b2 = d_in[20];
  const void* p2_proj_w = d_in[21];
  const void* p2_proj_b = d_in[22];
  const void* p2_w1 = d_in[23];
  const void* p2_b1 = d_in[24];
  const void* p2_w3 = d_in[25];
  const void* p2_b3 = d_in[26];
  const void* p2_w2 = d_in[27];
  const void* p2_b2 = d_in[28];

  // Workspace:
  //  [0,4)   hln -> ybuf (attn out) -> h1c (c-stream MLP hidden, 4 MiB)
  //  [4,12)  qk [T][2048]           -> (dead after attn)
  //  [12,16) v  [T][D]              -> (dead after attn)
  //  [4,16)  h1x (x-stream MLP hidden, exactly 12 MiB)
  //  [16,20) mid [T][D] bf16 (live to W2)
  //  [20,21) midln_c
  //  [21MB]  dtype flag
  //  [24,88) bf16-converted weights (only if ws_size >= 90 MB)
  //  midln_x = d_out[0,3MiB) scratch (consumed by W1/W3 before d_out is zeroed)
  char* ws = (char*)d_ws;
  unsigned short* hln     = (unsigned short*)(ws);
  unsigned short* ybuf    = (unsigned short*)(ws);
  unsigned short* h1c     = (unsigned short*)(ws);
  unsigned short* qkbuf   = (unsigned short*)(ws + ((size_t)4  << 20));
  unsigned short* h1x     = (unsigned short*)(ws + ((size_t)4  << 20));
  unsigned short* vbuf    = (unsigned short*)(ws + ((size_t)12 << 20));
  unsigned short* mid     = (unsigned short*)(ws + ((size_t)16 << 20));
  unsigned short* midln_c = (unsigned short*)(ws + ((size_t)20 << 20));
  int*            flag    = (int*)(ws + ((size_t)21 << 20));
  unsigned short* midln_x = (unsigned short*)d_out;
  unsigned short* hlnx    = hln + (size_t)S * D;

  // bf16 weight cache layout (element offsets from wbf)
  const bool conv = ws_size >= ((size_t)90 << 20);
  unsigned short* wbf = (unsigned short*)(ws + ((size_t)24 << 20));
  unsigned short* b_qk_c = wbf + 0;           // 2048x1024
  unsigned short* b_qk_x = wbf + 2097152;     // 2048x1024
  unsigned short* b_v_c  = wbf + 4194304;     // 1024x1024
  unsigned short* b_v_x  = wbf + 5242880;     // 1024x1024
  unsigned short* b_pj1  = wbf + 6291456;     // 1024x1024 (p1_proj_w)
  unsigned short* b_pj2  = wbf + 7340032;     // 1024x1024 (p2_proj_w)
  unsigned short* b_w1p1 = wbf + 8388608;     // 4096x1024
  unsigned short* b_w1p2 = wbf + 12582912;
  unsigned short* b_w3p1 = wbf + 16777216;
  unsigned short* b_w3p2 = wbf + 20971520;
  unsigned short* b_w2p1 = wbf + 25165824;    // 1024x4096
  unsigned short* b_w2p2 = wbf + 29360128;

  detect_kernel<<<1, 64, 0, stream>>>((const unsigned int*)px_qn, flag);

  if (conv) {
    CArgs ca;
    const void* ins[12]   = {pc_qk_w, px_qk_w, pc_v_w, px_v_w, p1_proj_w, p2_proj_w,
                             p1_w1, p2_w1, p1_w3, p2_w3, p1_w2, p2_w2};
    unsigned short* os[12] = {b_qk_c, b_qk_x, b_v_c, b_v_x, b_pj1, b_pj2,
                              b_w1p1, b_w1p2, b_w3p1, b_w3p2, b_w2p1, b_w2p2};
    unsigned int cnt[12]  = {262144, 262144, 131072, 131072, 131072, 131072,
                             524288, 524288, 524288, 524288, 524288, 524288};
    unsigned int cum = 0;
    for (int i = 0; i < 12; ++i) { ca.in[i] = ins[i]; ca.out[i] = os[i]; cum += cnt[i]; ca.cum[i] = cum; }
    convw_kernel<<<2048, 256, 0, stream>>>(ca, (int)cum, flag);
  }

  ln_ext_kernel<<<T, 256, 0, stream>>>(c, x, hln, flag);

  // P1: QKV (4 descriptors, one dispatch)
  {
    GArgs g = {};
    g.A[0] = hln;  g.bias[0] = nullptr; g.C[0] = qkbuf;                    g.mcum[0] = 4;  g.N[0] = 2048;
    g.A[1] = hlnx; g.bias[1] = nullptr; g.C[1] = qkbuf + (size_t)S * 2048; g.mcum[1] = 16; g.N[1] = 2048;
    g.A[2] = hln;  g.bias[2] = pc_v_b;  g.C[2] = vbuf;                     g.mcum[2] = 20; g.N[2] = 1024;
    g.A[3] = hlnx; g.bias[3] = px_v_b;  g.C[3] = vbuf + (size_t)S * D;     g.mcum[3] = 32; g.N[3] = 1024;
    g.K = 1024; g.nd = 4;
    if (conv) {
      g.B[0] = b_qk_c; g.B[1] = b_qk_x; g.B[2] = b_v_c; g.B[3] = b_v_x;
      gemm_kernel<0, 0, 1, 1><<<dim3(16, 32), 256, 0, stream>>>(g, flag);
    } else {
      g.B[0] = pc_qk_w; g.B[1] = px_qk_w; g.B[2] = pc_v_w; g.B[3] = px_v_w;
      gemm_kernel<0, 0, 1, 0><<<dim3(16, 32), 256, 0, stream>>>(g, flag);
    }
  }
  rmsrope_kernel<<<dim3(T, 4), 256, 0, stream>>>(qkbuf, pc_qn, pc_kn, px_qn, px_kn, freqs, flag);
  attn_kernel<<<512, 256, 0, stream>>>(qkbuf, vbuf, ybuf);

  // P2: out-projection + external residual -> mid
  {
    GArgs g = {};
    g.A[0] = ybuf;                  g.bias[0] = p2_proj_b; g.res[0] = c; g.C[0] = mid;                  g.mcum[0] = 4;  g.N[0] = 1024;
    g.A[1] = ybuf + (size_t)S * D;  g.bias[1] = p1_proj_b; g.res[1] = x; g.C[1] = mid + (size_t)S * D;  g.mcum[1] = 16; g.N[1] = 1024;
    g.K = 1024; g.nd = 2;
    if (conv) {
      g.B[0] = b_pj2; g.B[1] = b_pj1;
      gemm_kernel<1, 0, 1, 1><<<dim3(8, 16), 256, 0, stream>>>(g, flag);
    } else {
      g.B[0] = p2_proj_w; g.B[1] = p1_proj_w;
      gemm_kernel<1, 0, 1, 0><<<dim3(8, 16), 256, 0, stream>>>(g, flag);
    }
  }
  ln_mid_kernel<<<T, 256, 0, stream>>>(mid, midln_c, midln_x);

  // P3: W1 (x + c merged)
  {
    GArgs g = {};
    g.A[0] = midln_x; g.bias[0] = p1_b1; g.C[0] = h1x; g.mcum[0] = 12; g.N[0] = 4096;
    g.A[1] = midln_c; g.bias[1] = p2_b1; g.C[1] = h1c; g.mcum[1] = 16; g.N[1] = 4096;
    g.K = 1024; g.nd = 2;
    if (conv) {
      g.B[0] = b_w1p1; g.B[1] = b_w1p2;
      gemm_kernel<0, 0, 1, 1><<<dim3(32, 16), 256, 0, stream>>>(g, flag);
    } else {
      g.B[0] = p1_w1; g.B[1] = p2_w1;
      gemm_kernel<0, 0, 1, 0><<<dim3(32, 16), 256, 0, stream>>>(g, flag);
    }
  }
  // P4: W3 with fused silu(h1)*(acc+bias), in place
  {
    GArgs g = {};
    g.A[0] = midln_x; g.bias[0] = p1_b3; g.res[0] = h1x; g.C[0] = h1x; g.mcum[0] = 12; g.N[0] = 4096;
    g.A[1] = midln_c; g.bias[1] = p2_b3; g.res[1] = h1c; g.C[1] = h1c; g.mcum[1] = 16; g.N[1] = 4096;
    g.K = 1024; g.nd = 2;
    if (conv) {
      g.B[0] = b_w3p1; g.B[1] = b_w3p2;
      gemm_kernel<3, 0, 1, 1><<<dim3(32, 16), 256, 0, stream>>>(g, flag);
    } else {
      g.B[0] = p1_w3; g.B[1] = p2_w3;
      gemm_kernel<3, 0, 1, 0><<<dim3(32, 16), 256, 0, stream>>>(g, flag);
    }
  }
  // zero d_out, then P5: W2 split-K=4 atomics (+bias+res by slice 0)
  zero_kernel<<<2048, 256, 0, stream>>>(d_out, out_size, flag);
  {
    GArgs g = {};
    g.A[0] = h1x; g.bias[0] = p1_b2; g.res[0] = mid + (size_t)S * D; g.C[0] = d_out; g.oo[0] = 0;             g.mcum[0] = 12; g.N[0] = 1024;
    g.A[1] = h1c; g.bias[1] = p2_b2; g.res[1] = mid;                 g.C[1] = d_out; g.oo[1] = (size_t)L * D; g.mcum[1] = 16; g.N[1] = 1024;
    g.K = 4096; g.nd = 2;
    if (conv) {
      g.B[0] = b_w2p1; g.B[1] = b_w2p2;
      gemm_kernel<4, 2, 4, 1><<<dim3(8, 16, 4), 256, 0, stream>>>(g, flag);
    } else {
      g.B[0] = p1_w2; g.B[1] = p2_w2;
      gemm_kernel<4, 2, 4, 0><<<dim3(8, 16, 4), 256, 0, stream>>>(g, flag);
    }
  }
}